// Round 7
// baseline (725.392 us; speedup 1.0000x reference)
//
#include <hip/hip_runtime.h>
#include <hip/hip_bf16.h>

// StencilNet round 6: act staging via global_load_lds DMA (pre-swizzled global
// source, linear LDS dest), 2-deep B-frag prefetch ring. Structure otherwise
// = verified R5 (32x16 tile, 2 blocks/CU, zero-barrier tap loop).

#define HW   256
#define MASK 255
#define CH   64
#define TX   32
#define TY   16

typedef short bf16x8 __attribute__((ext_vector_type(8)));
typedef float f32x4  __attribute__((ext_vector_type(4)));

__device__ __forceinline__ float bf2f(unsigned short u) {
    return __uint_as_float(((unsigned int)u) << 16);
}
__device__ __forceinline__ unsigned short f2bf(float f) {
    unsigned int x = __float_as_uint(f);
    return (unsigned short)((x + 0x7fffu + ((x >> 16) & 1u)) >> 16);  // RNE
}

// ---- pack mid-layer weights into 16x16x32 B-frag layout (bf16) -------------
__global__ __launch_bounds__(512) void k_pack(
    const float* __restrict__ w1, const float* __restrict__ w2,
    const float* __restrict__ w3, const float* __restrict__ w4,
    unsigned short* __restrict__ dst)
{
    int g = blockIdx.x * 512 + threadIdx.x;
    if (g >= 4 * 4608) return;
    int L = g / 4608, r = g - L * 4608;
    const float* w = (L == 0) ? w1 : (L == 1) ? w2 : (L == 2) ? w3 : w4;
    int q = r >> 8, n = (r >> 6) & 3, l = r & 63;
    int tap = q >> 1, s = q & 1;
    int ci0 = s * 32 + ((l >> 4) << 3);
    int co  = n * 16 + (l & 15);
    unsigned short o8[8];
#pragma unroll
    for (int j = 0; j < 8; j++)
        o8[j] = f2bf(w[(tap * 64 + ci0 + j) * 64 + co]);
    *reinterpret_cast<uint4*>(dst + (size_t)g * 8) = *reinterpret_cast<uint4*>(o8);
}

// ---------------- Layer 0: [C,vx,vy] (3ch f32) -> 64ch bf16, ReLU -------------
__global__ __launch_bounds__(512) void k_layer0(
    const float* __restrict__ Cin, const float* __restrict__ vx,
    const float* __restrict__ vy, const float* __restrict__ w0,
    const float* __restrict__ b0, unsigned short* __restrict__ out)
{
    int t  = threadIdx.x;
    int lx = t & 31, ly = t >> 5;
    int x  = blockIdx.x * TX + lx;
    int y  = blockIdx.y * TY + ly;
    int bb = blockIdx.z;
    int pbase = bb * HW * HW;

    float a[27];
#pragma unroll
    for (int ky = 0; ky < 3; ky++) {
        int yy = (y + ky - 1) & MASK;
#pragma unroll
        for (int kx = 0; kx < 3; kx++) {
            int xx  = (x + kx - 1) & MASK;
            int idx = pbase + yy * HW + xx;
            a[(ky * 3 + kx) * 3 + 0] = Cin[idx];
            a[(ky * 3 + kx) * 3 + 1] = vx[idx];
            a[(ky * 3 + kx) * 3 + 2] = vy[idx];
        }
    }

    size_t obase = ((size_t)(pbase + y * HW + x)) * CH;
    for (int c4 = 0; c4 < 4; c4++) {
        float acc[16];
#pragma unroll
        for (int j = 0; j < 16; j++) acc[j] = b0[c4 * 16 + j];
#pragma unroll
        for (int k = 0; k < 27; k++) {
            float av = a[k];
            const float* wq = w0 + k * CH + c4 * 16;
#pragma unroll
            for (int j = 0; j < 16; j++) acc[j] = fmaf(av, wq[j], acc[j]);
        }
        unsigned short o[16];
#pragma unroll
        for (int j = 0; j < 16; j++) o[j] = f2bf(fmaxf(acc[j], 0.f));
        *reinterpret_cast<uint4*>(out + obase + c4 * 16)     = *reinterpret_cast<uint4*>(o);
        *reinterpret_cast<uint4*>(out + obase + c4 * 16 + 8) = *reinterpret_cast<uint4*>(o + 8);
    }
}

// ------------- Mid layers: DMA-staged act, zero-barrier tap loop -------------
__global__ __launch_bounds__(512, 4) void k_mid_v6(
    const unsigned short* __restrict__ in,
    const unsigned short* __restrict__ wp,   // packed B-frags for this layer
    const float* __restrict__ b, unsigned short* __restrict__ out)
{
    __shared__ unsigned short sAct[18 * 34 * CH];  // 78336 B -> 2 blocks/CU

    const int t    = threadIdx.x;
    const int lane = t & 63;
    const int wid  = t >> 6;
    const int l15  = lane & 15;
    const int l4   = lane >> 4;

    // bijective XCD-chunked swizzle: 1024 blocks = 8 chunks of 128
    const int bid = blockIdx.x;
    const int tid = (bid & 7) * 128 + (bid >> 3);
    const int bz  = tid >> 7;
    const int rr  = tid & 127;
    const int y0  = (rr >> 3) * 16;
    const int x0  = (rr & 7) * 32;
    const size_t pbase = (size_t)bz * HW * HW;

    // ---- stage act halo via global_load_lds DMA ----
    // LDS granule gg = hp*8 + so (linear, 16B each); global source channel
    // octet cg = so ^ (hp&7)  ==> LDS layout identical to verified R2 swizzle.
#pragma unroll
    for (int it = 0; it < 10; ++it) {
        int gg = it * 512 + t;
        if (gg < 4896) {
            int hp = gg >> 3, so = gg & 7;
            int cg = so ^ (hp & 7);
            int hr = hp / 34, hc = hp - hr * 34;
            int gy = (y0 + hr - 1) & MASK;
            int gx = (x0 + hc - 1) & MASK;
            const unsigned short* src =
                in + ((pbase + (size_t)gy * HW + gx) * CH + cg * 8);
            __builtin_amdgcn_global_load_lds(
                (const __attribute__((address_space(1))) unsigned int*)src,
                (__attribute__((address_space(3))) unsigned int*)&sAct[gg * 8],
                16, 0, 0);
        }
    }

    // 2-deep B-frag prefetch ring (static-indexed)
    bf16x8 bA[4], bB[4];
#pragma unroll
    for (int n = 0; n < 4; n++) {
        bA[n] = *reinterpret_cast<const bf16x8*>(wp + (size_t)((0 * 4 + n) * 512 + lane * 8));
        bB[n] = *reinterpret_cast<const bf16x8*>(wp + (size_t)((1 * 4 + n) * 512 + lane * 8));
    }

    __syncthreads();   // drains DMA + prefetch; the only barrier

    f32x4 acc[4][4];
#pragma unroll
    for (int m = 0; m < 4; m++)
#pragma unroll
        for (int n = 0; n < 4; n++) {
            float bv = b[n * 16 + l15];
            acc[m][n] = (f32x4){bv, bv, bv, bv};
        }

    int pxb[4];
#pragma unroll
    for (int m = 0; m < 4; m++)
        pxb[m] = (2 * wid + (m >> 1)) * 34 + (m & 1) * 16 + l15;

#pragma unroll
    for (int tap = 0; tap < 9; tap++) {
        const int koff = (tap / 3) * 34 + (tap % 3);
#pragma unroll
        for (int s = 0; s < 2; s++) {
            const int q = tap * 2 + s;
            bf16x8 bc[4];
#pragma unroll
            for (int n = 0; n < 4; n++) bc[n] = (q & 1) ? bB[n] : bA[n];
            if (q + 2 < 18) {
#pragma unroll
                for (int n = 0; n < 4; n++) {
                    bf16x8 v = *reinterpret_cast<const bf16x8*>(
                        wp + (size_t)(((q + 2) * 4 + n) * 512 + lane * 8));
                    if (q & 1) bB[n] = v; else bA[n] = v;
                }
            }
            const int o = s * 4 + l4;
#pragma unroll
            for (int m = 0; m < 4; m++) {
                int px  = pxb[m] + koff;
                int off = (px << 6) + (((o ^ px) & 7) << 3);
                bf16x8 af = *reinterpret_cast<const bf16x8*>(&sAct[off]);
#pragma unroll
                for (int n = 0; n < 4; n++)
                    acc[m][n] = __builtin_amdgcn_mfma_f32_16x16x32_bf16(
                        af, bc[n], acc[m][n], 0, 0, 0);
            }
        }
    }

    // ---- epilogue: ReLU -> bf16 (verified mapping) ----
#pragma unroll
    for (int m = 0; m < 4; m++) {
        int y = y0 + 2 * wid + (m >> 1);
        int x = x0 + (m & 1) * 16;
        unsigned short* pm = out + (pbase + (size_t)y * HW + x) * CH + (l4 << 8) + l15;
#pragma unroll
        for (int n = 0; n < 4; n++)
#pragma unroll
            for (int j = 0; j < 4; j++)
                pm[j * 64 + n * 16] = f2bf(fmaxf(acc[m][n][j], 0.f));
    }
}

// -------- Output layer MFMA: 64ch -> 16 coeffs + fused 4x4 stencil dot -------
__global__ __launch_bounds__(512, 2) void k_out_mfma(
    const unsigned short* __restrict__ in, const float* __restrict__ w,
    const float* __restrict__ b, const float* __restrict__ Cin,
    float* __restrict__ out)
{
    __shared__ unsigned short sAct[18 * 34 * CH];   // 78336 B
    __shared__ unsigned short sW[9 * 128 * 8];      // 18432 B
    __shared__ float sC[19 * 35];                   // 2660 B

    const int t    = threadIdx.x;
    const int lane = t & 63;
    const int wid  = t >> 6;
    const int l15  = lane & 15;
    const int l4   = lane >> 4;
    const int x0   = blockIdx.x * 32;
    const int y0   = blockIdx.y * 16;
    const size_t pbase = (size_t)blockIdx.z * HW * HW;

    // act halo via DMA (same pattern as k_mid_v6)
#pragma unroll
    for (int it = 0; it < 10; ++it) {
        int gg = it * 512 + t;
        if (gg < 4896) {
            int hp = gg >> 3, so = gg & 7;
            int cg = so ^ (hp & 7);
            int hr = hp / 34, hc = hp - hr * 34;
            int gy = (y0 + hr - 1) & MASK;
            int gx = (x0 + hc - 1) & MASK;
            const unsigned short* src =
                in + ((pbase + (size_t)gy * HW + gx) * CH + cg * 8);
            __builtin_amdgcn_global_load_lds(
                (const __attribute__((address_space(1))) unsigned int*)src,
                (__attribute__((address_space(3))) unsigned int*)&sAct[gg * 8],
                16, 0, 0);
        }
    }
    for (int g = t; g < 1152; g += 512) {
        int tap = g >> 7, s = (g >> 6) & 1, dl = g & 63;
        int ci0 = s * 32 + (dl >> 4) * 8;
        int co  = dl & 15;
        unsigned short o8[8];
#pragma unroll
        for (int j = 0; j < 8; j++)
            o8[j] = f2bf(w[(tap * 64 + ci0 + j) * 16 + co]);
        *reinterpret_cast<uint4*>(&sW[g * 8]) = *reinterpret_cast<uint4*>(o8);
    }
    for (int g = t; g < 19 * 35; g += 512) {
        int r = g / 35, c2 = g - r * 35;
        int gy = (y0 + r - 2) & MASK;
        int gx = (x0 + c2 - 2) & MASK;
        sC[g] = Cin[pbase + gy * HW + gx];
    }
    __syncthreads();

    f32x4 acc[4];
    {
        float bv = b[l15];
#pragma unroll
        for (int m = 0; m < 4; m++) acc[m] = (f32x4){bv, bv, bv, bv};
    }

    int pxb[4];
#pragma unroll
    for (int m = 0; m < 4; m++)
        pxb[m] = (2 * wid + (m >> 1)) * 34 + (m & 1) * 16 + l15;

    for (int tap = 0; tap < 9; tap++) {
        const int koff = (tap / 3) * 34 + (tap % 3);
#pragma unroll
        for (int s = 0; s < 2; s++) {
            bf16x8 bf = *reinterpret_cast<const bf16x8*>(
                &sW[((tap * 2 + s) << 9) + (lane << 3)]);
            const int o = s * 4 + l4;
#pragma unroll
            for (int m = 0; m < 4; m++) {
                int px  = pxb[m] + koff;
                int off = (px << 6) + (((o ^ px) & 7) << 3);
                bf16x8 af = *reinterpret_cast<const bf16x8*>(&sAct[off]);
                acc[m] = __builtin_amdgcn_mfma_f32_16x16x32_bf16(
                    af, bf, acc[m], 0, 0, 0);
            }
        }
    }

#pragma unroll
    for (int m = 0; m < 4; m++) {
        int py = 2 * wid + (m >> 1);
        int xb = (m & 1) * 16 + l4 * 4;
#pragma unroll
        for (int j = 0; j < 4; j++) {
            int xt = xb + j;
            float v = acc[m][j] * sC[(py + (l15 >> 2)) * 35 + xt + (l15 & 3)];
            v += __shfl_xor(v, 1);
            v += __shfl_xor(v, 2);
            v += __shfl_xor(v, 4);
            v += __shfl_xor(v, 8);
            if (l15 == 0)
                out[pbase + (y0 + py) * HW + x0 + xt] = v;
        }
    }
}

extern "C" void kernel_launch(void* const* d_in, const int* in_sizes, int n_in,
                              void* d_out, int out_size, void* d_ws, size_t ws_size,
                              hipStream_t stream)
{
    (void)in_sizes; (void)n_in; (void)out_size; (void)ws_size;
    const float* Cin  = (const float*)d_in[0];
    const float* vx   = (const float*)d_in[1];
    const float* vy   = (const float*)d_in[2];
    const float* w0   = (const float*)d_in[3];
    const float* b0   = (const float*)d_in[4];
    const float* w1   = (const float*)d_in[5];
    const float* b1   = (const float*)d_in[6];
    const float* w2   = (const float*)d_in[7];
    const float* b2   = (const float*)d_in[8];
    const float* w3   = (const float*)d_in[9];
    const float* b3   = (const float*)d_in[10];
    const float* w4   = (const float*)d_in[11];
    const float* b4   = (const float*)d_in[12];
    const float* wout = (const float*)d_in[13];
    const float* bout = (const float*)d_in[14];

    unsigned short* actA = (unsigned short*)d_ws;
    unsigned short* actB = actA + (size_t)8 * HW * HW * CH;

    unsigned short* wpk = (unsigned short*)d_out;   // parked; k_out rewrites

    dim3 block(512);
    dim3 grid0(HW / TX, HW / TY, 8);
    dim3 gridM(1024);
    dim3 gridO(HW / 32, HW / 16, 8);

    k_pack    <<<36, block, 0, stream>>>(w1, w2, w3, w4, wpk);
    k_layer0  <<<grid0, block, 0, stream>>>(Cin, vx, vy, w0, b0, actA);
    k_mid_v6  <<<gridM, block, 0, stream>>>(actA, wpk + 0 * 36864, b1, actB);
    k_mid_v6  <<<gridM, block, 0, stream>>>(actB, wpk + 1 * 36864, b2, actA);
    k_mid_v6  <<<gridM, block, 0, stream>>>(actA, wpk + 2 * 36864, b3, actB);
    k_mid_v6  <<<gridM, block, 0, stream>>>(actB, wpk + 3 * 36864, b4, actA);
    k_out_mfma<<<gridO, block, 0, stream>>>(actA, wout, bout, Cin, (float*)d_out);
}

// Round 8
// 316.694 us; speedup vs baseline: 2.2905x; 2.2905x over previous
//
#include <hip/hip_runtime.h>
#include <hip/hip_bf16.h>

// StencilNet round 7: revert R6's global_load_lds (per-lane LDS dest ->
// pathological codegen, 7x HBM amplification). Back to verified R5 structure
// with T14 staging: issue ALL global loads into VGPRs first, then all
// ds_writes -- breaks the per-iteration load->write latency chain.

#define HW   256
#define MASK 255
#define CH   64
#define TX   32
#define TY   16

typedef short bf16x8 __attribute__((ext_vector_type(8)));
typedef float f32x4  __attribute__((ext_vector_type(4)));

__device__ __forceinline__ float bf2f(unsigned short u) {
    return __uint_as_float(((unsigned int)u) << 16);
}
__device__ __forceinline__ unsigned short f2bf(float f) {
    unsigned int x = __float_as_uint(f);
    return (unsigned short)((x + 0x7fffu + ((x >> 16) & 1u)) >> 16);  // RNE
}

// ---- pack mid-layer weights into 16x16x32 B-frag layout (bf16) -------------
__global__ __launch_bounds__(512) void k_pack(
    const float* __restrict__ w1, const float* __restrict__ w2,
    const float* __restrict__ w3, const float* __restrict__ w4,
    unsigned short* __restrict__ dst)
{
    int g = blockIdx.x * 512 + threadIdx.x;
    if (g >= 4 * 4608) return;
    int L = g / 4608, r = g - L * 4608;
    const float* w = (L == 0) ? w1 : (L == 1) ? w2 : (L == 2) ? w3 : w4;
    int q = r >> 8, n = (r >> 6) & 3, l = r & 63;
    int tap = q >> 1, s = q & 1;
    int ci0 = s * 32 + ((l >> 4) << 3);
    int co  = n * 16 + (l & 15);
    unsigned short o8[8];
#pragma unroll
    for (int j = 0; j < 8; j++)
        o8[j] = f2bf(w[(tap * 64 + ci0 + j) * 64 + co]);
    *reinterpret_cast<uint4*>(dst + (size_t)g * 8) = *reinterpret_cast<uint4*>(o8);
}

// ---------------- Layer 0: [C,vx,vy] (3ch f32) -> 64ch bf16, ReLU -------------
__global__ __launch_bounds__(512) void k_layer0(
    const float* __restrict__ Cin, const float* __restrict__ vx,
    const float* __restrict__ vy, const float* __restrict__ w0,
    const float* __restrict__ b0, unsigned short* __restrict__ out)
{
    int t  = threadIdx.x;
    int lx = t & 31, ly = t >> 5;
    int x  = blockIdx.x * TX + lx;
    int y  = blockIdx.y * TY + ly;
    int bb = blockIdx.z;
    int pbase = bb * HW * HW;

    float a[27];
#pragma unroll
    for (int ky = 0; ky < 3; ky++) {
        int yy = (y + ky - 1) & MASK;
#pragma unroll
        for (int kx = 0; kx < 3; kx++) {
            int xx  = (x + kx - 1) & MASK;
            int idx = pbase + yy * HW + xx;
            a[(ky * 3 + kx) * 3 + 0] = Cin[idx];
            a[(ky * 3 + kx) * 3 + 1] = vx[idx];
            a[(ky * 3 + kx) * 3 + 2] = vy[idx];
        }
    }

    size_t obase = ((size_t)(pbase + y * HW + x)) * CH;
    for (int c4 = 0; c4 < 4; c4++) {
        float acc[16];
#pragma unroll
        for (int j = 0; j < 16; j++) acc[j] = b0[c4 * 16 + j];
#pragma unroll
        for (int k = 0; k < 27; k++) {
            float av = a[k];
            const float* wq = w0 + k * CH + c4 * 16;
#pragma unroll
            for (int j = 0; j < 16; j++) acc[j] = fmaf(av, wq[j], acc[j]);
        }
        unsigned short o[16];
#pragma unroll
        for (int j = 0; j < 16; j++) o[j] = f2bf(fmaxf(acc[j], 0.f));
        *reinterpret_cast<uint4*>(out + obase + c4 * 16)     = *reinterpret_cast<uint4*>(o);
        *reinterpret_cast<uint4*>(out + obase + c4 * 16 + 8) = *reinterpret_cast<uint4*>(o + 8);
    }
}

// ------------- Mid layers: T14 reg-staged act, zero-barrier tap loop ---------
__global__ __launch_bounds__(512, 4) void k_mid_v7(
    const unsigned short* __restrict__ in,
    const unsigned short* __restrict__ wp,   // packed B-frags for this layer
    const float* __restrict__ b, unsigned short* __restrict__ out)
{
    __shared__ unsigned short sAct[18 * 34 * CH];  // 78336 B -> 2 blocks/CU

    const int t    = threadIdx.x;
    const int lane = t & 63;
    const int wid  = t >> 6;
    const int l15  = lane & 15;
    const int l4   = lane >> 4;

    // bijective XCD-chunked swizzle: 1024 blocks = 8 chunks of 128
    const int bid = blockIdx.x;
    const int tid = (bid & 7) * 128 + (bid >> 3);
    const int bz  = tid >> 7;
    const int rr  = tid & 127;
    const int y0  = (rr >> 3) * 16;
    const int x0  = (rr & 7) * 32;
    const size_t pbase = (size_t)bz * HW * HW;

    // ---- T14 staging: issue all loads -> regs, then all ds_writes ----
    uint4 st[10];
#pragma unroll
    for (int it = 0; it < 10; ++it) {
        int gg = it * 512 + t;
        if (gg < 4896) {
            int hp = gg >> 3, cg = gg & 7;
            int hr = hp / 34, hc = hp - hr * 34;
            int gy = (y0 + hr - 1) & MASK;
            int gx = (x0 + hc - 1) & MASK;
            st[it] = *reinterpret_cast<const uint4*>(
                in + ((pbase + (size_t)gy * HW + gx) * CH + cg * 8));
        }
    }

    // B-frag prefetch for q=0 (overlaps with outstanding staging loads)
    bf16x8 bnx[4];
#pragma unroll
    for (int n = 0; n < 4; n++)
        bnx[n] = *reinterpret_cast<const bf16x8*>(wp + (size_t)(n * 512 + lane * 8));

#pragma unroll
    for (int it = 0; it < 10; ++it) {
        int gg = it * 512 + t;
        if (gg < 4896) {
            int hp = gg >> 3, cg = gg & 7;
            *reinterpret_cast<uint4*>(
                &sAct[hp * 64 + ((cg ^ (hp & 7)) << 3)]) = st[it];
        }
    }

    __syncthreads();   // the only barrier

    f32x4 acc[4][4];
#pragma unroll
    for (int m = 0; m < 4; m++)
#pragma unroll
        for (int n = 0; n < 4; n++) {
            float bv = b[n * 16 + l15];
            acc[m][n] = (f32x4){bv, bv, bv, bv};
        }

    int pxb[4];
#pragma unroll
    for (int m = 0; m < 4; m++)
        pxb[m] = (2 * wid + (m >> 1)) * 34 + (m & 1) * 16 + l15;

#pragma unroll
    for (int tap = 0; tap < 9; tap++) {
        const int koff = (tap / 3) * 34 + (tap % 3);
#pragma unroll
        for (int s = 0; s < 2; s++) {
            const int q = tap * 2 + s;
            bf16x8 bc[4];
#pragma unroll
            for (int n = 0; n < 4; n++) bc[n] = bnx[n];
            if (q < 17) {
#pragma unroll
                for (int n = 0; n < 4; n++)
                    bnx[n] = *reinterpret_cast<const bf16x8*>(
                        wp + (size_t)(((q + 1) * 4 + n) * 512 + lane * 8));
            }
            const int o = s * 4 + l4;
#pragma unroll
            for (int m = 0; m < 4; m++) {
                int px  = pxb[m] + koff;
                int off = (px << 6) + (((o ^ px) & 7) << 3);
                bf16x8 af = *reinterpret_cast<const bf16x8*>(&sAct[off]);
#pragma unroll
                for (int n = 0; n < 4; n++)
                    acc[m][n] = __builtin_amdgcn_mfma_f32_16x16x32_bf16(
                        af, bc[n], acc[m][n], 0, 0, 0);
            }
        }
    }

    // ---- epilogue: ReLU -> bf16 (verified mapping) ----
#pragma unroll
    for (int m = 0; m < 4; m++) {
        int y = y0 + 2 * wid + (m >> 1);
        int x = x0 + (m & 1) * 16;
        unsigned short* pm = out + (pbase + (size_t)y * HW + x) * CH + (l4 << 8) + l15;
#pragma unroll
        for (int n = 0; n < 4; n++)
#pragma unroll
            for (int j = 0; j < 4; j++)
                pm[j * 64 + n * 16] = f2bf(fmaxf(acc[m][n][j], 0.f));
    }
}

// -------- Output layer MFMA: 64ch -> 16 coeffs + fused 4x4 stencil dot -------
__global__ __launch_bounds__(512, 2) void k_out_mfma(
    const unsigned short* __restrict__ in, const float* __restrict__ w,
    const float* __restrict__ b, const float* __restrict__ Cin,
    float* __restrict__ out)
{
    __shared__ unsigned short sAct[18 * 34 * CH];   // 78336 B
    __shared__ unsigned short sW[9 * 128 * 8];      // 18432 B
    __shared__ float sC[19 * 35];                   // 2660 B

    const int t    = threadIdx.x;
    const int lane = t & 63;
    const int wid  = t >> 6;
    const int l15  = lane & 15;
    const int l4   = lane >> 4;
    const int x0   = blockIdx.x * 32;
    const int y0   = blockIdx.y * 16;
    const size_t pbase = (size_t)blockIdx.z * HW * HW;

    // T14 act staging (same as k_mid_v7)
    uint4 st[10];
#pragma unroll
    for (int it = 0; it < 10; ++it) {
        int gg = it * 512 + t;
        if (gg < 4896) {
            int hp = gg >> 3, cg = gg & 7;
            int hr = hp / 34, hc = hp - hr * 34;
            int gy = (y0 + hr - 1) & MASK;
            int gx = (x0 + hc - 1) & MASK;
            st[it] = *reinterpret_cast<const uint4*>(
                in + ((pbase + (size_t)gy * HW + gx) * CH + cg * 8));
        }
    }
#pragma unroll
    for (int it = 0; it < 10; ++it) {
        int gg = it * 512 + t;
        if (gg < 4896) {
            int hp = gg >> 3, cg = gg & 7;
            *reinterpret_cast<uint4*>(
                &sAct[hp * 64 + ((cg ^ (hp & 7)) << 3)]) = st[it];
        }
    }
    for (int g = t; g < 1152; g += 512) {
        int tap = g >> 7, s = (g >> 6) & 1, dl = g & 63;
        int ci0 = s * 32 + (dl >> 4) * 8;
        int co  = dl & 15;
        unsigned short o8[8];
#pragma unroll
        for (int j = 0; j < 8; j++)
            o8[j] = f2bf(w[(tap * 64 + ci0 + j) * 16 + co]);
        *reinterpret_cast<uint4*>(&sW[g * 8]) = *reinterpret_cast<uint4*>(o8);
    }
    for (int g = t; g < 19 * 35; g += 512) {
        int r = g / 35, c2 = g - r * 35;
        int gy = (y0 + r - 2) & MASK;
        int gx = (x0 + c2 - 2) & MASK;
        sC[g] = Cin[pbase + gy * HW + gx];
    }
    __syncthreads();

    f32x4 acc[4];
    {
        float bv = b[l15];
#pragma unroll
        for (int m = 0; m < 4; m++) acc[m] = (f32x4){bv, bv, bv, bv};
    }

    int pxb[4];
#pragma unroll
    for (int m = 0; m < 4; m++)
        pxb[m] = (2 * wid + (m >> 1)) * 34 + (m & 1) * 16 + l15;

    for (int tap = 0; tap < 9; tap++) {
        const int koff = (tap / 3) * 34 + (tap % 3);
#pragma unroll
        for (int s = 0; s < 2; s++) {
            bf16x8 bf = *reinterpret_cast<const bf16x8*>(
                &sW[((tap * 2 + s) << 9) + (lane << 3)]);
            const int o = s * 4 + l4;
#pragma unroll
            for (int m = 0; m < 4; m++) {
                int px  = pxb[m] + koff;
                int off = (px << 6) + (((o ^ px) & 7) << 3);
                bf16x8 af = *reinterpret_cast<const bf16x8*>(&sAct[off]);
                acc[m] = __builtin_amdgcn_mfma_f32_16x16x32_bf16(
                    af, bf, acc[m], 0, 0, 0);
            }
        }
    }

#pragma unroll
    for (int m = 0; m < 4; m++) {
        int py = 2 * wid + (m >> 1);
        int xb = (m & 1) * 16 + l4 * 4;
#pragma unroll
        for (int j = 0; j < 4; j++) {
            int xt = xb + j;
            float v = acc[m][j] * sC[(py + (l15 >> 2)) * 35 + xt + (l15 & 3)];
            v += __shfl_xor(v, 1);
            v += __shfl_xor(v, 2);
            v += __shfl_xor(v, 4);
            v += __shfl_xor(v, 8);
            if (l15 == 0)
                out[pbase + (y0 + py) * HW + x0 + xt] = v;
        }
    }
}

extern "C" void kernel_launch(void* const* d_in, const int* in_sizes, int n_in,
                              void* d_out, int out_size, void* d_ws, size_t ws_size,
                              hipStream_t stream)
{
    (void)in_sizes; (void)n_in; (void)out_size; (void)ws_size;
    const float* Cin  = (const float*)d_in[0];
    const float* vx   = (const float*)d_in[1];
    const float* vy   = (const float*)d_in[2];
    const float* w0   = (const float*)d_in[3];
    const float* b0   = (const float*)d_in[4];
    const float* w1   = (const float*)d_in[5];
    const float* b1   = (const float*)d_in[6];
    const float* w2   = (const float*)d_in[7];
    const float* b2   = (const float*)d_in[8];
    const float* w3   = (const float*)d_in[9];
    const float* b3   = (const float*)d_in[10];
    const float* w4   = (const float*)d_in[11];
    const float* b4   = (const float*)d_in[12];
    const float* wout = (const float*)d_in[13];
    const float* bout = (const float*)d_in[14];

    unsigned short* actA = (unsigned short*)d_ws;
    unsigned short* actB = actA + (size_t)8 * HW * HW * CH;

    unsigned short* wpk = (unsigned short*)d_out;   // parked; k_out rewrites

    dim3 block(512);
    dim3 grid0(HW / TX, HW / TY, 8);
    dim3 gridM(1024);
    dim3 gridO(HW / 32, HW / 16, 8);

    k_pack    <<<36, block, 0, stream>>>(w1, w2, w3, w4, wpk);
    k_layer0  <<<grid0, block, 0, stream>>>(Cin, vx, vy, w0, b0, actA);
    k_mid_v7  <<<gridM, block, 0, stream>>>(actA, wpk + 0 * 36864, b1, actB);
    k_mid_v7  <<<gridM, block, 0, stream>>>(actB, wpk + 1 * 36864, b2, actA);
    k_mid_v7  <<<gridM, block, 0, stream>>>(actA, wpk + 2 * 36864, b3, actB);
    k_mid_v7  <<<gridM, block, 0, stream>>>(actB, wpk + 3 * 36864, b4, actA);
    k_out_mfma<<<gridO, block, 0, stream>>>(actA, wout, bout, Cin, (float*)d_out);
}

// Round 9
// 263.898 us; speedup vs baseline: 2.7488x; 1.2001x over previous
//
#include <hip/hip_runtime.h>
#include <hip/hip_bf16.h>

// StencilNet round 8: R7's T14 staging spilled st[10] to scratch (WRITE_SIZE
// 65->144MB). Fix: unconditional wrap-mapped granules (no divergent defs) in
// two passes of 5 (20 live VGPRs), loads batched before writes. Structure
// otherwise = verified R5 (32x16 tile, 2 blocks/CU, zero-barrier tap loop).

#define HW   256
#define MASK 255
#define CH   64
#define TX   32
#define TY   16

typedef short bf16x8 __attribute__((ext_vector_type(8)));
typedef float f32x4  __attribute__((ext_vector_type(4)));

__device__ __forceinline__ float bf2f(unsigned short u) {
    return __uint_as_float(((unsigned int)u) << 16);
}
__device__ __forceinline__ unsigned short f2bf(float f) {
    unsigned int x = __float_as_uint(f);
    return (unsigned short)((x + 0x7fffu + ((x >> 16) & 1u)) >> 16);  // RNE
}

// ---- pack mid-layer weights into 16x16x32 B-frag layout (bf16) -------------
__global__ __launch_bounds__(512) void k_pack(
    const float* __restrict__ w1, const float* __restrict__ w2,
    const float* __restrict__ w3, const float* __restrict__ w4,
    unsigned short* __restrict__ dst)
{
    int g = blockIdx.x * 512 + threadIdx.x;
    if (g >= 4 * 4608) return;
    int L = g / 4608, r = g - L * 4608;
    const float* w = (L == 0) ? w1 : (L == 1) ? w2 : (L == 2) ? w3 : w4;
    int q = r >> 8, n = (r >> 6) & 3, l = r & 63;
    int tap = q >> 1, s = q & 1;
    int ci0 = s * 32 + ((l >> 4) << 3);
    int co  = n * 16 + (l & 15);
    unsigned short o8[8];
#pragma unroll
    for (int j = 0; j < 8; j++)
        o8[j] = f2bf(w[(tap * 64 + ci0 + j) * 64 + co]);
    *reinterpret_cast<uint4*>(dst + (size_t)g * 8) = *reinterpret_cast<uint4*>(o8);
}

// ---------------- Layer 0: [C,vx,vy] (3ch f32) -> 64ch bf16, ReLU -------------
__global__ __launch_bounds__(512) void k_layer0(
    const float* __restrict__ Cin, const float* __restrict__ vx,
    const float* __restrict__ vy, const float* __restrict__ w0,
    const float* __restrict__ b0, unsigned short* __restrict__ out)
{
    int t  = threadIdx.x;
    int lx = t & 31, ly = t >> 5;
    int x  = blockIdx.x * TX + lx;
    int y  = blockIdx.y * TY + ly;
    int bb = blockIdx.z;
    int pbase = bb * HW * HW;

    float a[27];
#pragma unroll
    for (int ky = 0; ky < 3; ky++) {
        int yy = (y + ky - 1) & MASK;
#pragma unroll
        for (int kx = 0; kx < 3; kx++) {
            int xx  = (x + kx - 1) & MASK;
            int idx = pbase + yy * HW + xx;
            a[(ky * 3 + kx) * 3 + 0] = Cin[idx];
            a[(ky * 3 + kx) * 3 + 1] = vx[idx];
            a[(ky * 3 + kx) * 3 + 2] = vy[idx];
        }
    }

    size_t obase = ((size_t)(pbase + y * HW + x)) * CH;
    for (int c4 = 0; c4 < 4; c4++) {
        float acc[16];
#pragma unroll
        for (int j = 0; j < 16; j++) acc[j] = b0[c4 * 16 + j];
#pragma unroll
        for (int k = 0; k < 27; k++) {
            float av = a[k];
            const float* wq = w0 + k * CH + c4 * 16;
#pragma unroll
            for (int j = 0; j < 16; j++) acc[j] = fmaf(av, wq[j], acc[j]);
        }
        unsigned short o[16];
#pragma unroll
        for (int j = 0; j < 16; j++) o[j] = f2bf(fmaxf(acc[j], 0.f));
        *reinterpret_cast<uint4*>(out + obase + c4 * 16)     = *reinterpret_cast<uint4*>(o);
        *reinterpret_cast<uint4*>(out + obase + c4 * 16 + 8) = *reinterpret_cast<uint4*>(o + 8);
    }
}

// ------------- Mid layers: low-pressure batched staging, zero-barrier loop ---
__global__ __launch_bounds__(512, 4) void k_mid_v8(
    const unsigned short* __restrict__ in,
    const unsigned short* __restrict__ wp,   // packed B-frags for this layer
    const float* __restrict__ b, unsigned short* __restrict__ out)
{
    __shared__ unsigned short sAct[18 * 34 * CH];  // 78336 B -> 2 blocks/CU

    const int t    = threadIdx.x;
    const int lane = t & 63;
    const int wid  = t >> 6;
    const int l15  = lane & 15;
    const int l4   = lane >> 4;

    // bijective XCD-chunked swizzle: 1024 blocks = 8 chunks of 128
    const int bid = blockIdx.x;
    const int tid = (bid & 7) * 128 + (bid >> 3);
    const int bz  = tid >> 7;
    const int rr  = tid & 127;
    const int y0  = (rr >> 3) * 16;
    const int x0  = (rr & 7) * 32;
    const size_t pbase = (size_t)bz * HW * HW;

    // B-frag prefetch for q=0 first (its latency hides under staging)
    bf16x8 bnx[4];
#pragma unroll
    for (int n = 0; n < 4; n++)
        bnx[n] = *reinterpret_cast<const bf16x8*>(wp + (size_t)(n * 512 + lane * 8));

    // ---- staging: 2 passes x 5 granules, unconditional (wrap-mapped) ----
    // total granules 18*34*8 = 4896; indices >= 4896 wrap to 0..223 and
    // duplicate-write identical data (benign).
#pragma unroll
    for (int half = 0; half < 2; ++half) {
        uint4 st[5];
#pragma unroll
        for (int it = 0; it < 5; ++it) {
            int gg = (half * 5 + it) * 512 + t;
            if (gg >= 4896) gg -= 4896;
            int hp = gg >> 3, cg = gg & 7;
            int hr = hp / 34, hc = hp - hr * 34;
            int gy = (y0 + hr - 1) & MASK;
            int gx = (x0 + hc - 1) & MASK;
            st[it] = *reinterpret_cast<const uint4*>(
                in + ((pbase + (size_t)gy * HW + gx) * CH + cg * 8));
        }
#pragma unroll
        for (int it = 0; it < 5; ++it) {
            int gg = (half * 5 + it) * 512 + t;
            if (gg >= 4896) gg -= 4896;
            int hp = gg >> 3, cg = gg & 7;
            *reinterpret_cast<uint4*>(
                &sAct[hp * 64 + ((cg ^ (hp & 7)) << 3)]) = st[it];
        }
    }

    __syncthreads();   // the only barrier

    f32x4 acc[4][4];
#pragma unroll
    for (int m = 0; m < 4; m++)
#pragma unroll
        for (int n = 0; n < 4; n++) {
            float bv = b[n * 16 + l15];
            acc[m][n] = (f32x4){bv, bv, bv, bv};
        }

    int pxb[4];
#pragma unroll
    for (int m = 0; m < 4; m++)
        pxb[m] = (2 * wid + (m >> 1)) * 34 + (m & 1) * 16 + l15;

#pragma unroll
    for (int tap = 0; tap < 9; tap++) {
        const int koff = (tap / 3) * 34 + (tap % 3);
#pragma unroll
        for (int s = 0; s < 2; s++) {
            const int q = tap * 2 + s;
            bf16x8 bc[4];
#pragma unroll
            for (int n = 0; n < 4; n++) bc[n] = bnx[n];
            if (q < 17) {
#pragma unroll
                for (int n = 0; n < 4; n++)
                    bnx[n] = *reinterpret_cast<const bf16x8*>(
                        wp + (size_t)(((q + 1) * 4 + n) * 512 + lane * 8));
            }
            const int o = s * 4 + l4;
#pragma unroll
            for (int m = 0; m < 4; m++) {
                int px  = pxb[m] + koff;
                int off = (px << 6) + (((o ^ px) & 7) << 3);
                bf16x8 af = *reinterpret_cast<const bf16x8*>(&sAct[off]);
#pragma unroll
                for (int n = 0; n < 4; n++)
                    acc[m][n] = __builtin_amdgcn_mfma_f32_16x16x32_bf16(
                        af, bc[n], acc[m][n], 0, 0, 0);
            }
        }
    }

    // ---- epilogue: ReLU -> bf16 (verified mapping) ----
#pragma unroll
    for (int m = 0; m < 4; m++) {
        int y = y0 + 2 * wid + (m >> 1);
        int x = x0 + (m & 1) * 16;
        unsigned short* pm = out + (pbase + (size_t)y * HW + x) * CH + (l4 << 8) + l15;
#pragma unroll
        for (int n = 0; n < 4; n++)
#pragma unroll
            for (int j = 0; j < 4; j++)
                pm[j * 64 + n * 16] = f2bf(fmaxf(acc[m][n][j], 0.f));
    }
}

// -------- Output layer MFMA: 64ch -> 16 coeffs + fused 4x4 stencil dot -------
__global__ __launch_bounds__(512, 2) void k_out_mfma(
    const unsigned short* __restrict__ in, const float* __restrict__ w,
    const float* __restrict__ b, const float* __restrict__ Cin,
    float* __restrict__ out)
{
    __shared__ unsigned short sAct[18 * 34 * CH];   // 78336 B
    __shared__ unsigned short sW[9 * 128 * 8];      // 18432 B
    __shared__ float sC[19 * 35];                   // 2660 B

    const int t    = threadIdx.x;
    const int lane = t & 63;
    const int wid  = t >> 6;
    const int l15  = lane & 15;
    const int l4   = lane >> 4;
    const int x0   = blockIdx.x * 32;
    const int y0   = blockIdx.y * 16;
    const size_t pbase = (size_t)blockIdx.z * HW * HW;

    // act staging: same 2x5 unconditional batched pattern
#pragma unroll
    for (int half = 0; half < 2; ++half) {
        uint4 st[5];
#pragma unroll
        for (int it = 0; it < 5; ++it) {
            int gg = (half * 5 + it) * 512 + t;
            if (gg >= 4896) gg -= 4896;
            int hp = gg >> 3, cg = gg & 7;
            int hr = hp / 34, hc = hp - hr * 34;
            int gy = (y0 + hr - 1) & MASK;
            int gx = (x0 + hc - 1) & MASK;
            st[it] = *reinterpret_cast<const uint4*>(
                in + ((pbase + (size_t)gy * HW + gx) * CH + cg * 8));
        }
#pragma unroll
        for (int it = 0; it < 5; ++it) {
            int gg = (half * 5 + it) * 512 + t;
            if (gg >= 4896) gg -= 4896;
            int hp = gg >> 3, cg = gg & 7;
            *reinterpret_cast<uint4*>(
                &sAct[hp * 64 + ((cg ^ (hp & 7)) << 3)]) = st[it];
        }
    }
    for (int g = t; g < 1152; g += 512) {
        int tap = g >> 7, s = (g >> 6) & 1, dl = g & 63;
        int ci0 = s * 32 + (dl >> 4) * 8;
        int co  = dl & 15;
        unsigned short o8[8];
#pragma unroll
        for (int j = 0; j < 8; j++)
            o8[j] = f2bf(w[(tap * 64 + ci0 + j) * 16 + co]);
        *reinterpret_cast<uint4*>(&sW[g * 8]) = *reinterpret_cast<uint4*>(o8);
    }
    for (int g = t; g < 19 * 35; g += 512) {
        int r = g / 35, c2 = g - r * 35;
        int gy = (y0 + r - 2) & MASK;
        int gx = (x0 + c2 - 2) & MASK;
        sC[g] = Cin[pbase + gy * HW + gx];
    }
    __syncthreads();

    f32x4 acc[4];
    {
        float bv = b[l15];
#pragma unroll
        for (int m = 0; m < 4; m++) acc[m] = (f32x4){bv, bv, bv, bv};
    }

    int pxb[4];
#pragma unroll
    for (int m = 0; m < 4; m++)
        pxb[m] = (2 * wid + (m >> 1)) * 34 + (m & 1) * 16 + l15;

    for (int tap = 0; tap < 9; tap++) {
        const int koff = (tap / 3) * 34 + (tap % 3);
#pragma unroll
        for (int s = 0; s < 2; s++) {
            bf16x8 bf = *reinterpret_cast<const bf16x8*>(
                &sW[((tap * 2 + s) << 9) + (lane << 3)]);
            const int o = s * 4 + l4;
#pragma unroll
            for (int m = 0; m < 4; m++) {
                int px  = pxb[m] + koff;
                int off = (px << 6) + (((o ^ px) & 7) << 3);
                bf16x8 af = *reinterpret_cast<const bf16x8*>(&sAct[off]);
                acc[m] = __builtin_amdgcn_mfma_f32_16x16x32_bf16(
                    af, bf, acc[m], 0, 0, 0);
            }
        }
    }

#pragma unroll
    for (int m = 0; m < 4; m++) {
        int py = 2 * wid + (m >> 1);
        int xb = (m & 1) * 16 + l4 * 4;
#pragma unroll
        for (int j = 0; j < 4; j++) {
            int xt = xb + j;
            float v = acc[m][j] * sC[(py + (l15 >> 2)) * 35 + xt + (l15 & 3)];
            v += __shfl_xor(v, 1);
            v += __shfl_xor(v, 2);
            v += __shfl_xor(v, 4);
            v += __shfl_xor(v, 8);
            if (l15 == 0)
                out[pbase + (y0 + py) * HW + x0 + xt] = v;
        }
    }
}

extern "C" void kernel_launch(void* const* d_in, const int* in_sizes, int n_in,
                              void* d_out, int out_size, void* d_ws, size_t ws_size,
                              hipStream_t stream)
{
    (void)in_sizes; (void)n_in; (void)out_size; (void)ws_size;
    const float* Cin  = (const float*)d_in[0];
    const float* vx   = (const float*)d_in[1];
    const float* vy   = (const float*)d_in[2];
    const float* w0   = (const float*)d_in[3];
    const float* b0   = (const float*)d_in[4];
    const float* w1   = (const float*)d_in[5];
    const float* b1   = (const float*)d_in[6];
    const float* w2   = (const float*)d_in[7];
    const float* b2   = (const float*)d_in[8];
    const float* w3   = (const float*)d_in[9];
    const float* b3   = (const float*)d_in[10];
    const float* w4   = (const float*)d_in[11];
    const float* b4   = (const float*)d_in[12];
    const float* wout = (const float*)d_in[13];
    const float* bout = (const float*)d_in[14];

    unsigned short* actA = (unsigned short*)d_ws;
    unsigned short* actB = actA + (size_t)8 * HW * HW * CH;

    unsigned short* wpk = (unsigned short*)d_out;   // parked; k_out rewrites

    dim3 block(512);
    dim3 grid0(HW / TX, HW / TY, 8);
    dim3 gridM(1024);
    dim3 gridO(HW / 32, HW / 16, 8);

    k_pack    <<<36, block, 0, stream>>>(w1, w2, w3, w4, wpk);
    k_layer0  <<<grid0, block, 0, stream>>>(Cin, vx, vy, w0, b0, actA);
    k_mid_v8  <<<gridM, block, 0, stream>>>(actA, wpk + 0 * 36864, b1, actB);
    k_mid_v8  <<<gridM, block, 0, stream>>>(actB, wpk + 1 * 36864, b2, actA);
    k_mid_v8  <<<gridM, block, 0, stream>>>(actA, wpk + 2 * 36864, b3, actB);
    k_mid_v8  <<<gridM, block, 0, stream>>>(actB, wpk + 3 * 36864, b4, actA);
    k_out_mfma<<<gridO, block, 0, stream>>>(actA, wout, bout, Cin, (float*)d_out);
}